// Round 16
// baseline (218.637 us; speedup 1.0000x reference)
//
#include <hip/hip_runtime.h>

// MHA: B=4, S=2048, D_MODEL=512, H=8, D_HEAD=64
// prep (Wt transpose + QKV fp32->bf16, one launch) -> qkv GEMMs (gl_lds, r14)
// -> flash attn (r16: V direct-to-register dbuf, K gl_lds dbuf, ONE barrier/tile)
// -> out proj GEMM. r15 lesson: keep convert as a streaming pass (BW-bound,
// latency-hidden), never as in-GEMM reg staging.

typedef unsigned short u16;
typedef __bf16 bf16x8 __attribute__((ext_vector_type(8)));
typedef float  f32x4  __attribute__((ext_vector_type(4)));

__device__ __forceinline__ u16 f2bf(float x) {
  unsigned u = __float_as_uint(x);
  u += 0x7fffu + ((u >> 16) & 1u);   // RNE
  return (u16)(u >> 16);
}

__device__ __forceinline__ unsigned cvtpk(float lo, float hi) {
  unsigned r;
  asm("v_cvt_pk_bf16_f32 %0, %1, %2" : "=v"(r) : "v"(lo), "v"(hi));
  return r;
}

__device__ __forceinline__ f32x4 mfma16(bf16x8 a, bf16x8 b, f32x4 c) {
  return __builtin_amdgcn_mfma_f32_16x16x32_bf16(a, b, c, 0, 0, 0);
}

// async 16B/lane global->LDS; lds dest is wave-uniform base (HW adds lane*16)
__device__ __forceinline__ void gl16(const u16* g, u16* l) {
  __builtin_amdgcn_global_load_lds(
      (const __attribute__((address_space(1))) void*)g,
      (__attribute__((address_space(3))) void*)l, 16, 0, 0);
}

#define MX3(a, b, c) fmaxf(fmaxf((a), (b)), (c))

// ---- prep: Wt transpose (y=0..3) + Q/K/V fp32->bf16 convert (y=4..6) ----
__global__ __launch_bounds__(256) void prep_k(const float* __restrict__ W0,
                                              const float* __restrict__ W1,
                                              const float* __restrict__ W2,
                                              const float* __restrict__ W3,
                                              u16* __restrict__ Wt,
                                              const float* __restrict__ Q,
                                              const float* __restrict__ K,
                                              const float* __restrict__ V,
                                              u16* __restrict__ Oq,
                                              u16* __restrict__ Ok,
                                              u16* __restrict__ Ov) {
  int y = blockIdx.y;
  if (y < 4) {
    if (blockIdx.x >= 1024) return;
    const float* W = y == 0 ? W0 : y == 1 ? W1 : y == 2 ? W2 : W3;
    int idx = blockIdx.x * 256 + threadIdx.x;
    int k = idx >> 9, n = idx & 511;
    Wt[y * 262144 + n * 512 + k] = f2bf(W[idx]);
  } else {
    int sel = y - 4;
    const float* X = sel == 0 ? Q : sel == 1 ? K : V;
    u16* O = sel == 0 ? Oq : sel == 1 ? Ok : Ov;
    size_t i = ((size_t)blockIdx.x * 256 + threadIdx.x) * 8;
    float4 a = *(const float4*)(X + i);
    float4 b = *(const float4*)(X + i + 4);
    uint4 pk = make_uint4(cvtpk(a.x, a.y), cvtpk(a.z, a.w),
                          cvtpk(b.x, b.y), cvtpk(b.z, b.w));
    *(uint4*)(O + i) = pk;
  }
}

// ---- m97-style bf16 GEMM: A[8192x512] @ Bt^T + bias (Bt [n][k] bf16) ----
// OUT_MODE: 0 bf16 [m][n], 1 bf16 vT[(b*8+h)*64+d][s], 2 fp32 [m][n]
template <int OUT_MODE, int BN>
__device__ __forceinline__ void gemm_body(const u16* __restrict__ A,
                                          const u16* __restrict__ Bt,
                                          const float* __restrict__ bias,
                                          void* __restrict__ outp, int bidx) {
  constexpr int NF = BN / 32;
  constexpr int NBN = 512 / BN;
  __shared__ __align__(16) u16 As[128][64];
  __shared__ __align__(16) u16 Bs[BN][64];
  int tid = threadIdx.x;
  int lane = tid & 63, wid = tid >> 6;
  int wm = wid >> 1, wn = wid & 1;
  int lr = lane & 15, lg = lane >> 4;
  int bm = bidx / NBN, bn = bidx % NBN;

  int r0 = tid >> 3;
  int c8s = (tid & 7) ^ (r0 & 7);
  const u16* Ab = A + (size_t)(bm * 128) * 512;
  const u16* Bb = Bt + (size_t)(bn * BN) * 512;

  f32x4 acc[4][NF];
#pragma unroll
  for (int i = 0; i < 4; ++i)
#pragma unroll
    for (int j = 0; j < NF; ++j) {
      f32x4 z = {0.f, 0.f, 0.f, 0.f};
      acc[i][j] = z;
    }

#pragma unroll
  for (int kt = 0; kt < 8; ++kt) {
    int k0 = kt * 64;
#pragma unroll
    for (int i = 0; i < 4; ++i)
      gl16(&Ab[(size_t)(i * 32 + r0) * 512 + k0 + c8s * 8],
           &As[0][0] + i * 2048 + wid * 512);
#pragma unroll
    for (int i = 0; i < BN / 32; ++i)
      gl16(&Bb[(size_t)(i * 32 + r0) * 512 + k0 + c8s * 8],
           &Bs[0][0] + i * 2048 + wid * 512);
    __syncthreads();
#pragma unroll
    for (int kk = 0; kk < 2; ++kk) {
      bf16x8 af[4], bfr[NF];
      int sw = (lr & 7) << 3;
#pragma unroll
      for (int mf = 0; mf < 4; ++mf)
        af[mf] = *(const bf16x8*)&As[wm * 64 + mf * 16 + lr][(kk * 32 + lg * 8) ^ sw];
#pragma unroll
      for (int nf = 0; nf < NF; ++nf)
        bfr[nf] = *(const bf16x8*)&Bs[wn * (BN / 2) + nf * 16 + lr][(kk * 32 + lg * 8) ^ sw];
#pragma unroll
      for (int mf = 0; mf < 4; ++mf)
#pragma unroll
        for (int nf = 0; nf < NF; ++nf)
          acc[mf][nf] = mfma16(af[mf], bfr[nf], acc[mf][nf]);
    }
    __syncthreads();
  }

#pragma unroll
  for (int mf = 0; mf < 4; ++mf) {
#pragma unroll
    for (int nf = 0; nf < NF; ++nf) {
      int m = bm * 128 + wm * 64 + mf * 16 + lg * 4;
      int n = bn * BN + wn * (BN / 2) + nf * 16 + lr;
      float bia = bias[n];
      if (OUT_MODE == 0) {
        u16* o = (u16*)outp;
#pragma unroll
        for (int r = 0; r < 4; ++r)
          o[(size_t)(m + r) * 512 + n] = f2bf(acc[mf][nf][r] + bia);
      } else if (OUT_MODE == 2) {
        float* o = (float*)outp;
#pragma unroll
        for (int r = 0; r < 4; ++r)
          o[(size_t)(m + r) * 512 + n] = acc[mf][nf][r] + bia;
      } else {
        u16* o = (u16*)outp;
        int b = m >> 11, s = m & 2047;
        int h = n >> 6, d = n & 63;
        ushort4 pk = make_ushort4(f2bf(acc[mf][nf][0] + bia), f2bf(acc[mf][nf][1] + bia),
                                  f2bf(acc[mf][nf][2] + bia), f2bf(acc[mf][nf][3] + bia));
        *(ushort4*)&o[(size_t)((b * 8 + h) * 64 + d) * 2048 + s] = pk;
      }
    }
  }
}

__global__ __launch_bounds__(256) void qkv_k(const u16* __restrict__ Aq,
                                             const u16* __restrict__ Ak,
                                             const u16* __restrict__ Av,
                                             const u16* __restrict__ Wt,
                                             const float* __restrict__ bq,
                                             const float* __restrict__ bk,
                                             const float* __restrict__ bv,
                                             u16* __restrict__ outbase) {
  int sel = blockIdx.y;
  const u16* A = sel == 0 ? Aq : sel == 1 ? Ak : Av;
  const float* bia = sel == 0 ? bq : sel == 1 ? bk : bv;
  const u16* Bt = Wt + (size_t)sel * 262144;
  u16* out = outbase + (size_t)sel * 8192 * 512;
  if (sel == 2)
    gemm_body<1, 128>(A, Bt, bia, out, blockIdx.x);
  else
    gemm_body<0, 128>(A, Bt, bia, out, blockIdx.x);
}

__global__ __launch_bounds__(256) void gemm_out_k(const u16* __restrict__ Ap,
                                                  const u16* __restrict__ Bt,
                                                  const float* __restrict__ bias,
                                                  void* __restrict__ outp) {
  gemm_body<2, 64>(Ap, Bt, bias, outp, blockIdx.x);
}

// ---- flash attention r16: V direct-to-register (dbuf), K gl_lds dbuf,
// ONE barrier per tile. Compute/softmax path = r14 verbatim. ----
__global__ __launch_bounds__(256) void attn_k(const u16* __restrict__ q,
                                              const u16* __restrict__ kmat,
                                              const u16* __restrict__ vT,
                                              u16* __restrict__ z) {
  __shared__ __align__(16) u16 Ks[2][64][64];   // [buf][key][d], swizzled content
  __shared__ __align__(16) u16 Ps[4][16][72];   // per-wave P[q][key]
  const float C = 0.125f * 1.44269504f;         // 1/sqrt(64) * log2(e)
  int tid = threadIdx.x;
  int lane = tid & 63, w = tid >> 6;
  int lr = lane & 15, lg = lane >> 4;
  int bh = blockIdx.x >> 5, qt = blockIdx.x & 31;
  int b = bh >> 3, h = bh & 7;
  size_t qrow0 = (size_t)(b * 2048 + qt * 64 + w * 16);

  bf16x8 qf[2];
#pragma unroll
  for (int kf = 0; kf < 2; ++kf)
    qf[kf] = *(const bf16x8*)&q[(qrow0 + lr) * 512 + h * 64 + kf * 32 + lg * 8];

  f32x4 oacc[4];
#pragma unroll
  for (int j = 0; j < 4; ++j) {
    f32x4 zf = {0.f, 0.f, 0.f, 0.f};
    oacc[j] = zf;
  }
  float m = -1e30f, l_part = 0.f, negmC = 0.f;

  const u16* kbase = kmat + (size_t)(b * 2048) * 512 + h * 64;
  const u16* vbase = vT + (size_t)(bh * 64) * 2048;
  // per-lane V fragment base: row = nfo*16+lr (d), col = kt*64 + ks*32 + lg*8 (s)
  const u16* vfrag = vbase + (size_t)lr * 2048 + lg * 8;

  int r0 = tid >> 3;                         // 0..31
  int c8s = (tid & 7) ^ (r0 & 7);
  int sw = (lr & 7) << 3;                    // Ks fragment-read swizzle

  bf16x8 vb0[2][4], vb1[2][4];

  // prologue: K(0) -> buf0; vb0 <- V(0)
  gl16(&kbase[(size_t)r0 * 512 + c8s * 8],        &Ks[0][0][0] + w * 512);
  gl16(&kbase[(size_t)(r0 + 32) * 512 + c8s * 8], &Ks[0][0][0] + 2048 + w * 512);
#pragma unroll
  for (int ks = 0; ks < 2; ++ks)
#pragma unroll
    for (int nfo = 0; nfo < 4; ++nfo)
      vb0[ks][nfo] = *(const bf16x8*)&vfrag[(size_t)(nfo * 16) * 2048 + ks * 32];
  asm volatile("s_waitcnt vmcnt(0)" ::: "memory");
  __syncthreads();

  // one KV tile: Kc = current K buffer, Kn = next; vbu = V regs for this tile,
  // vbl = V regs to fill for next tile.
  auto tile = [&](int kt, const u16* Kc, u16* Kn,
                  bf16x8 (&vbu)[2][4], bf16x8 (&vbl)[2][4]) {
    // issue K(kt+1) (buffer free since last barrier) and vb(kt+1) loads
    if (kt < 31) {
      gl16(&kbase[(size_t)((kt + 1) * 64 + r0) * 512 + c8s * 8],      Kn + w * 512);
      gl16(&kbase[(size_t)((kt + 1) * 64 + r0 + 32) * 512 + c8s * 8], Kn + 2048 + w * 512);
      const u16* vf = vfrag + (kt + 1) * 64;
#pragma unroll
      for (int ks = 0; ks < 2; ++ks)
#pragma unroll
        for (int nfo = 0; nfo < 4; ++nfo)
          vbl[ks][nfo] = *(const bf16x8*)&vf[(size_t)(nfo * 16) * 2048 + ks * 32];
    }

    // S^T = K @ Q^T : sacc[nf][r] = S[q=lr][key = nf*16 + lg*4 + r]
    f32x4 sacc[4];
#pragma unroll
    for (int j = 0; j < 4; ++j) {
      f32x4 zf = {0.f, 0.f, 0.f, 0.f};
      sacc[j] = zf;
    }
#pragma unroll
    for (int kf = 0; kf < 2; ++kf) {
#pragma unroll
      for (int nf = 0; nf < 4; ++nf) {
        int row = nf * 16 + lr;
        bf16x8 kb = *(const bf16x8*)&Kc[row * 64 + ((kf * 32 + lg * 8) ^ sw)];
        sacc[nf] = mfma16(kb, qf[kf], sacc[nf]);
      }
    }

    // lane-local 16-value max via max3 triples
    float t0 = MX3(sacc[0][0], sacc[0][1], sacc[0][2]);
    float t1 = MX3(sacc[0][3], sacc[1][0], sacc[1][1]);
    float t2 = MX3(sacc[1][2], sacc[1][3], sacc[2][0]);
    float t3 = MX3(sacc[2][1], sacc[2][2], sacc[2][3]);
    float t4 = MX3(sacc[3][0], sacc[3][1], sacc[3][2]);
    float mxl = fmaxf(MX3(t0, t1, t2), MX3(t3, t4, sacc[3][3]));

    // defer-max: lane-local test exact; shuffles + rescale only in rare branch
    if (!__all(mxl - m <= 8.f)) {
      float mx = fmaxf(mxl, __shfl_xor(mxl, 16));
      mx = fmaxf(mx, __shfl_xor(mx, 32));
      float mnew = fmaxf(m, mx);
      float sc = __builtin_amdgcn_exp2f((m - mnew) * C);
      m = mnew;
      negmC = -m * C;
      l_part *= sc;
#pragma unroll
      for (int nfo = 0; nfo < 4; ++nfo)
#pragma unroll
        for (int r = 0; r < 4; ++r) oacc[nfo][r] *= sc;
    }

    // P = exp2(S*C - m*C); per-lane partial sum; pack to Ps
    float rsum = 0.f;
#pragma unroll
    for (int nf = 0; nf < 4; ++nf) {
      float p0 = __builtin_amdgcn_exp2f(fmaf(sacc[nf][0], C, negmC));
      float p1 = __builtin_amdgcn_exp2f(fmaf(sacc[nf][1], C, negmC));
      float p2 = __builtin_amdgcn_exp2f(fmaf(sacc[nf][2], C, negmC));
      float p3 = __builtin_amdgcn_exp2f(fmaf(sacc[nf][3], C, negmC));
      rsum += (p0 + p1) + (p2 + p3);
      uint2 pw = make_uint2(cvtpk(p0, p1), cvtpk(p2, p3));
      *(uint2*)&Ps[w][lr][nf * 16 + lg * 4] = pw;
    }
    l_part += rsum;

    // Ps write->read ordering: proven fence pair (wave-private, no barrier)
    asm volatile("s_waitcnt lgkmcnt(0)" ::: "memory");
    __builtin_amdgcn_sched_barrier(0);

    // O^T += V^T @ P^T using this tile's V registers
#pragma unroll
    for (int ks = 0; ks < 2; ++ks) {
      bf16x8 pa = *(const bf16x8*)&Ps[w][lr][ks * 32 + lg * 8];
#pragma unroll
      for (int nfo = 0; nfo < 4; ++nfo)
        oacc[nfo] = mfma16(vbu[ks][nfo], pa, oacc[nfo]);
    }

    // single end-of-tile barrier: K(kt+1) + vb(kt+1) landed; Ks[cur] reads done
    asm volatile("s_waitcnt vmcnt(0)" ::: "memory");
    __syncthreads();
  };

  for (int ko = 0; ko < 32; ko += 2) {
    tile(ko,     &Ks[0][0][0], &Ks[1][0][0], vb0, vb1);
    tile(ko + 1, &Ks[1][0][0], &Ks[0][0][0], vb1, vb0);
  }

  float l = l_part + __shfl_xor(l_part, 16);
  l += __shfl_xor(l, 32);
  float rl = 1.f / l;
#pragma unroll
  for (int nfo = 0; nfo < 4; ++nfo) {
    uint2 pw = make_uint2(cvtpk(oacc[nfo][0] * rl, oacc[nfo][1] * rl),
                          cvtpk(oacc[nfo][2] * rl, oacc[nfo][3] * rl));
    *(uint2*)&z[(qrow0 + lr) * 512 + h * 64 + nfo * 16 + lg * 4] = pw;
  }
}

extern "C" void kernel_launch(void* const* d_in, const int* in_sizes, int n_in,
                              void* d_out, int out_size, void* d_ws, size_t ws_size,
                              hipStream_t stream) {
  const float* Q  = (const float*)d_in[0];
  const float* K  = (const float*)d_in[1];
  const float* V  = (const float*)d_in[2];
  const float* Wq = (const float*)d_in[3];
  const float* bq = (const float*)d_in[4];
  const float* Wk = (const float*)d_in[5];
  const float* bk = (const float*)d_in[6];
  const float* Wv = (const float*)d_in[7];
  const float* bv = (const float*)d_in[8];
  const float* Wo = (const float*)d_in[9];
  const float* bo = (const float*)d_in[10];
  float* out = (float*)d_out;

  u16* ws  = (u16*)d_ws;
  u16* Wt  = ws;                                   // 4 x 512*512 (q,k,v,o)
  u16* qws = Wt + 4 * 262144;                      // 8192*512 each
  u16* kws = qws + (size_t)8192 * 512;
  u16* vTw = kws + (size_t)8192 * 512;             // [(b*8+h)*64+d][2048]
  u16* zws = vTw + (size_t)8192 * 512;

  // bf16 copies of Q/K/V in regions dead until later stages:
  // AbfQ/AbfK in d_out (overwritten only by final gemm_out), AbfV in zws
  // (attn writes zws only after qkv finished reading AbfV).
  u16* AbfQ = (u16*)d_out;
  u16* AbfK = AbfQ + (size_t)8192 * 512;
  u16* AbfV = zws;

  prep_k<<<dim3(2048, 7), 256, 0, stream>>>(Wq, Wk, Wv, Wo, Wt, Q, K, V,
                                            AbfQ, AbfK, AbfV);
  qkv_k<<<dim3(256, 3), 256, 0, stream>>>(AbfQ, AbfK, AbfV, Wt, bq, bk, bv, qws);
  attn_k<<<1024, 256, 0, stream>>>(qws, kws, vTw, zws);
  gemm_out_k<<<512, 256, 0, stream>>>(zws, Wt + 3 * 262144, bo, out);
}

// Round 17
// 114.312 us; speedup vs baseline: 1.9126x; 1.9126x over previous
//
#include <hip/hip_runtime.h>

// MHA: B=4, S=2048, D_MODEL=512, H=8, D_HEAD=64
// prep (Wt transpose + QKV fp32->bf16) -> qkv GEMMs (gl_lds, r14) ->
// flash attn (r17: r14 per-wave pipeline, 8-wave/512-thread blocks, QBLK=128 ->
// half the K/V traffic & staging instrs, same 16 waves/CU) -> out proj GEMM.
// r16 lesson: V must stay LDS-staged (per-lane V frags are uncoalesced, 170us).

typedef unsigned short u16;
typedef __bf16 bf16x8 __attribute__((ext_vector_type(8)));
typedef float  f32x4  __attribute__((ext_vector_type(4)));

__device__ __forceinline__ u16 f2bf(float x) {
  unsigned u = __float_as_uint(x);
  u += 0x7fffu + ((u >> 16) & 1u);   // RNE
  return (u16)(u >> 16);
}

__device__ __forceinline__ unsigned cvtpk(float lo, float hi) {
  unsigned r;
  asm("v_cvt_pk_bf16_f32 %0, %1, %2" : "=v"(r) : "v"(lo), "v"(hi));
  return r;
}

__device__ __forceinline__ f32x4 mfma16(bf16x8 a, bf16x8 b, f32x4 c) {
  return __builtin_amdgcn_mfma_f32_16x16x32_bf16(a, b, c, 0, 0, 0);
}

// async 16B/lane global->LDS; lds dest is wave-uniform base (HW adds lane*16)
__device__ __forceinline__ void gl16(const u16* g, u16* l) {
  __builtin_amdgcn_global_load_lds(
      (const __attribute__((address_space(1))) void*)g,
      (__attribute__((address_space(3))) void*)l, 16, 0, 0);
}

#define MX3(a, b, c) fmaxf(fmaxf((a), (b)), (c))

// ---- prep: Wt transpose (y=0..3) + Q/K/V fp32->bf16 convert (y=4..6) ----
__global__ __launch_bounds__(256) void prep_k(const float* __restrict__ W0,
                                              const float* __restrict__ W1,
                                              const float* __restrict__ W2,
                                              const float* __restrict__ W3,
                                              u16* __restrict__ Wt,
                                              const float* __restrict__ Q,
                                              const float* __restrict__ K,
                                              const float* __restrict__ V,
                                              u16* __restrict__ Oq,
                                              u16* __restrict__ Ok,
                                              u16* __restrict__ Ov) {
  int y = blockIdx.y;
  if (y < 4) {
    if (blockIdx.x >= 1024) return;
    const float* W = y == 0 ? W0 : y == 1 ? W1 : y == 2 ? W2 : W3;
    int idx = blockIdx.x * 256 + threadIdx.x;
    int k = idx >> 9, n = idx & 511;
    Wt[y * 262144 + n * 512 + k] = f2bf(W[idx]);
  } else {
    int sel = y - 4;
    const float* X = sel == 0 ? Q : sel == 1 ? K : V;
    u16* O = sel == 0 ? Oq : sel == 1 ? Ok : Ov;
    size_t i = ((size_t)blockIdx.x * 256 + threadIdx.x) * 8;
    float4 a = *(const float4*)(X + i);
    float4 b = *(const float4*)(X + i + 4);
    uint4 pk = make_uint4(cvtpk(a.x, a.y), cvtpk(a.z, a.w),
                          cvtpk(b.x, b.y), cvtpk(b.z, b.w));
    *(uint4*)(O + i) = pk;
  }
}

// ---- m97-style bf16 GEMM: A[8192x512] @ Bt^T + bias (Bt [n][k] bf16) ----
// OUT_MODE: 0 bf16 [m][n], 1 bf16 vT[(b*8+h)*64+d][s], 2 fp32 [m][n]
template <int OUT_MODE, int BN>
__device__ __forceinline__ void gemm_body(const u16* __restrict__ A,
                                          const u16* __restrict__ Bt,
                                          const float* __restrict__ bias,
                                          void* __restrict__ outp, int bidx) {
  constexpr int NF = BN / 32;
  constexpr int NBN = 512 / BN;
  __shared__ __align__(16) u16 As[128][64];
  __shared__ __align__(16) u16 Bs[BN][64];
  int tid = threadIdx.x;
  int lane = tid & 63, wid = tid >> 6;
  int wm = wid >> 1, wn = wid & 1;
  int lr = lane & 15, lg = lane >> 4;
  int bm = bidx / NBN, bn = bidx % NBN;

  int r0 = tid >> 3;
  int c8s = (tid & 7) ^ (r0 & 7);
  const u16* Ab = A + (size_t)(bm * 128) * 512;
  const u16* Bb = Bt + (size_t)(bn * BN) * 512;

  f32x4 acc[4][NF];
#pragma unroll
  for (int i = 0; i < 4; ++i)
#pragma unroll
    for (int j = 0; j < NF; ++j) {
      f32x4 z = {0.f, 0.f, 0.f, 0.f};
      acc[i][j] = z;
    }

#pragma unroll
  for (int kt = 0; kt < 8; ++kt) {
    int k0 = kt * 64;
#pragma unroll
    for (int i = 0; i < 4; ++i)
      gl16(&Ab[(size_t)(i * 32 + r0) * 512 + k0 + c8s * 8],
           &As[0][0] + i * 2048 + wid * 512);
#pragma unroll
    for (int i = 0; i < BN / 32; ++i)
      gl16(&Bb[(size_t)(i * 32 + r0) * 512 + k0 + c8s * 8],
           &Bs[0][0] + i * 2048 + wid * 512);
    __syncthreads();
#pragma unroll
    for (int kk = 0; kk < 2; ++kk) {
      bf16x8 af[4], bfr[NF];
      int sw = (lr & 7) << 3;
#pragma unroll
      for (int mf = 0; mf < 4; ++mf)
        af[mf] = *(const bf16x8*)&As[wm * 64 + mf * 16 + lr][(kk * 32 + lg * 8) ^ sw];
#pragma unroll
      for (int nf = 0; nf < NF; ++nf)
        bfr[nf] = *(const bf16x8*)&Bs[wn * (BN / 2) + nf * 16 + lr][(kk * 32 + lg * 8) ^ sw];
#pragma unroll
      for (int mf = 0; mf < 4; ++mf)
#pragma unroll
        for (int nf = 0; nf < NF; ++nf)
          acc[mf][nf] = mfma16(af[mf], bfr[nf], acc[mf][nf]);
    }
    __syncthreads();
  }

#pragma unroll
  for (int mf = 0; mf < 4; ++mf) {
#pragma unroll
    for (int nf = 0; nf < NF; ++nf) {
      int m = bm * 128 + wm * 64 + mf * 16 + lg * 4;
      int n = bn * BN + wn * (BN / 2) + nf * 16 + lr;
      float bia = bias[n];
      if (OUT_MODE == 0) {
        u16* o = (u16*)outp;
#pragma unroll
        for (int r = 0; r < 4; ++r)
          o[(size_t)(m + r) * 512 + n] = f2bf(acc[mf][nf][r] + bia);
      } else if (OUT_MODE == 2) {
        float* o = (float*)outp;
#pragma unroll
        for (int r = 0; r < 4; ++r)
          o[(size_t)(m + r) * 512 + n] = acc[mf][nf][r] + bia;
      } else {
        u16* o = (u16*)outp;
        int b = m >> 11, s = m & 2047;
        int h = n >> 6, d = n & 63;
        ushort4 pk = make_ushort4(f2bf(acc[mf][nf][0] + bia), f2bf(acc[mf][nf][1] + bia),
                                  f2bf(acc[mf][nf][2] + bia), f2bf(acc[mf][nf][3] + bia));
        *(ushort4*)&o[(size_t)((b * 8 + h) * 64 + d) * 2048 + s] = pk;
      }
    }
  }
}

__global__ __launch_bounds__(256) void qkv_k(const u16* __restrict__ Aq,
                                             const u16* __restrict__ Ak,
                                             const u16* __restrict__ Av,
                                             const u16* __restrict__ Wt,
                                             const float* __restrict__ bq,
                                             const float* __restrict__ bk,
                                             const float* __restrict__ bv,
                                             u16* __restrict__ outbase) {
  int sel = blockIdx.y;
  const u16* A = sel == 0 ? Aq : sel == 1 ? Ak : Av;
  const float* bia = sel == 0 ? bq : sel == 1 ? bk : bv;
  const u16* Bt = Wt + (size_t)sel * 262144;
  u16* out = outbase + (size_t)sel * 8192 * 512;
  if (sel == 2)
    gemm_body<1, 128>(A, Bt, bia, out, blockIdx.x);
  else
    gemm_body<0, 128>(A, Bt, bia, out, blockIdx.x);
}

__global__ __launch_bounds__(256) void gemm_out_k(const u16* __restrict__ Ap,
                                                  const u16* __restrict__ Bt,
                                                  const float* __restrict__ bias,
                                                  void* __restrict__ outp) {
  gemm_body<2, 64>(Ap, Bt, bias, outp, blockIdx.x);
}

// ---- flash attention r17: r14 per-wave pipeline, 8 waves/block, QBLK=128 ----
// Each 512-thread block: one 64-key K/V tile serves 128 q-rows (16/wave).
// Staging: 1 gl16/thread for K, 1 for V per tile (half of r14's per-thread work,
// half the block count -> half the K/V fetch traffic).
__global__ __launch_bounds__(512) void attn_k(const u16* __restrict__ q,
                                              const u16* __restrict__ kmat,
                                              const u16* __restrict__ vT,
                                              u16* __restrict__ z) {
  __shared__ __align__(16) u16 Ks[2][64][64];   // [buf][key][d], swizzled content
  __shared__ __align__(16) u16 Vs[64][64];      // [d][key], swizzled content
  __shared__ __align__(16) u16 Ps[8][16][72];   // per-wave P[q][key]
  const float C = 0.125f * 1.44269504f;         // 1/sqrt(64) * log2(e)
  int tid = threadIdx.x;
  int lane = tid & 63, w = tid >> 6;            // w = 0..7
  int lr = lane & 15, lg = lane >> 4;
  int bh = blockIdx.x >> 4, qt = blockIdx.x & 15;
  int b = bh >> 3, h = bh & 7;
  size_t qrow0 = (size_t)(b * 2048 + qt * 128 + w * 16);

  bf16x8 qf[2];
#pragma unroll
  for (int kf = 0; kf < 2; ++kf)
    qf[kf] = *(const bf16x8*)&q[(qrow0 + lr) * 512 + h * 64 + kf * 32 + lg * 8];

  f32x4 oacc[4];
#pragma unroll
  for (int j = 0; j < 4; ++j) {
    f32x4 zf = {0.f, 0.f, 0.f, 0.f};
    oacc[j] = zf;
  }
  float m = -1e30f, l_part = 0.f, negmC = 0.f;

  const u16* kbase = kmat + (size_t)(b * 2048) * 512 + h * 64;
  const u16* vbase = vT + (size_t)(bh * 64) * 2048;

  int r0 = tid >> 3;                         // 0..63 (512 threads cover 64 rows)
  int c8s = (tid & 7) ^ (r0 & 7);
  int sw = (lr & 7) << 3;                    // fragment-read swizzle (row&7 == lr&7)
  // prologue: K(0) -> buf0 (one gl16/thread covers the whole 64x64 tile)
  gl16(&kbase[(size_t)r0 * 512 + c8s * 8], &Ks[0][0][0] + w * 512);
  asm volatile("s_waitcnt vmcnt(0)" ::: "memory");
  __syncthreads();

  // one KV tile; Kc = current K buffer (literal per call site), Kn = next
  auto tile = [&](int kt, const u16* Kc, u16* Kn) {
    // issue V(kt) (waited mid-tile via vmcnt), then K(kt+1) (stays in flight)
    gl16(&vbase[(size_t)r0 * 2048 + kt * 64 + c8s * 8], &Vs[0][0] + w * 512);
    if (kt < 31)
      gl16(&kbase[(size_t)((kt + 1) * 64 + r0) * 512 + c8s * 8], Kn + w * 512);

    // S^T = K @ Q^T : sacc[nf][r] = S[q=lr][key = nf*16 + lg*4 + r]
    f32x4 sacc[4];
#pragma unroll
    for (int j = 0; j < 4; ++j) {
      f32x4 zf = {0.f, 0.f, 0.f, 0.f};
      sacc[j] = zf;
    }
#pragma unroll
    for (int kf = 0; kf < 2; ++kf) {
#pragma unroll
      for (int nf = 0; nf < 4; ++nf) {
        int row = nf * 16 + lr;
        bf16x8 kb = *(const bf16x8*)&Kc[row * 64 + ((kf * 32 + lg * 8) ^ sw)];
        sacc[nf] = mfma16(kb, qf[kf], sacc[nf]);
      }
    }

    // lane-local 16-value max via max3 triples (8 ops)
    float t0 = MX3(sacc[0][0], sacc[0][1], sacc[0][2]);
    float t1 = MX3(sacc[0][3], sacc[1][0], sacc[1][1]);
    float t2 = MX3(sacc[1][2], sacc[1][3], sacc[2][0]);
    float t3 = MX3(sacc[2][1], sacc[2][2], sacc[2][3]);
    float t4 = MX3(sacc[3][0], sacc[3][1], sacc[3][2]);
    float mxl = fmaxf(MX3(t0, t1, t2), MX3(t3, t4, sacc[3][3]));

    // defer-max: lane-local test exact; shuffles + rescale only in rare branch
    if (!__all(mxl - m <= 8.f)) {
      float mx = fmaxf(mxl, __shfl_xor(mxl, 16));
      mx = fmaxf(mx, __shfl_xor(mx, 32));
      float mnew = fmaxf(m, mx);
      float sc = __builtin_amdgcn_exp2f((m - mnew) * C);
      m = mnew;
      negmC = -m * C;
      l_part *= sc;
#pragma unroll
      for (int nfo = 0; nfo < 4; ++nfo)
#pragma unroll
        for (int r = 0; r < 4; ++r) oacc[nfo][r] *= sc;
    }

    // P = exp2(S*C - m*C); per-lane partial sum; pack to Ps
    float rsum = 0.f;
#pragma unroll
    for (int nf = 0; nf < 4; ++nf) {
      float p0 = __builtin_amdgcn_exp2f(fmaf(sacc[nf][0], C, negmC));
      float p1 = __builtin_amdgcn_exp2f(fmaf(sacc[nf][1], C, negmC));
      float p2 = __builtin_amdgcn_exp2f(fmaf(sacc[nf][2], C, negmC));
      float p3 = __builtin_amdgcn_exp2f(fmaf(sacc[nf][3], C, negmC));
      rsum += (p0 + p1) + (p2 + p3);
      uint2 pw = make_uint2(cvtpk(p0, p1), cvtpk(p2, p3));
      *(uint2*)&Ps[w][lr][nf * 16 + lg * 4] = pw;
    }
    l_part += rsum;

    // order Ps writes before Ps reads; wait V(kt) landed (K prefetch in flight)
    asm volatile("s_waitcnt lgkmcnt(0)" ::: "memory");
    if (kt < 31) {
      asm volatile("s_waitcnt vmcnt(1)" ::: "memory");
    } else {
      asm volatile("s_waitcnt vmcnt(0)" ::: "memory");
    }
    __builtin_amdgcn_s_barrier();

    // O^T += V^T @ P^T
#pragma unroll
    for (int ks = 0; ks < 2; ++ks) {
      bf16x8 pa = *(const bf16x8*)&Ps[w][lr][ks * 32 + lg * 8];
#pragma unroll
      for (int nfo = 0; nfo < 4; ++nfo) {
        int row = nfo * 16 + lr;
        bf16x8 vbr = *(const bf16x8*)&Vs[row][(ks * 32 + lg * 8) ^ sw];
        oacc[nfo] = mfma16(vbr, pa, oacc[nfo]);
      }
    }
    __syncthreads();
  };

  for (int ko = 0; ko < 32; ko += 2) {
    tile(ko,     &Ks[0][0][0], &Ks[1][0][0]);
    tile(ko + 1, &Ks[1][0][0], &Ks[0][0][0]);
  }

  // combine per-lane l partials once (row = lanes {lr, lr+16, lr+32, lr+48})
  float l = l_part + __shfl_xor(l_part, 16);
  l += __shfl_xor(l, 32);
  float rl = 1.f / l;
#pragma unroll
  for (int nfo = 0; nfo < 4; ++nfo) {
    uint2 pw = make_uint2(cvtpk(oacc[nfo][0] * rl, oacc[nfo][1] * rl),
                          cvtpk(oacc[nfo][2] * rl, oacc[nfo][3] * rl));
    *(uint2*)&z[(qrow0 + lr) * 512 + h * 64 + nfo * 16 + lg * 4] = pw;
  }
}

extern "C" void kernel_launch(void* const* d_in, const int* in_sizes, int n_in,
                              void* d_out, int out_size, void* d_ws, size_t ws_size,
                              hipStream_t stream) {
  const float* Q  = (const float*)d_in[0];
  const float* K  = (const float*)d_in[1];
  const float* V  = (const float*)d_in[2];
  const float* Wq = (const float*)d_in[3];
  const float* bq = (const float*)d_in[4];
  const float* Wk = (const float*)d_in[5];
  const float* bk = (const float*)d_in[6];
  const float* Wv = (const float*)d_in[7];
  const float* bv = (const float*)d_in[8];
  const float* Wo = (const float*)d_in[9];
  const float* bo = (const float*)d_in[10];
  float* out = (float*)d_out;

  u16* ws  = (u16*)d_ws;
  u16* Wt  = ws;                                   // 4 x 512*512 (q,k,v,o)
  u16* qws = Wt + 4 * 262144;                      // 8192*512 each
  u16* kws = qws + (size_t)8192 * 512;
  u16* vTw = kws + (size_t)8192 * 512;             // [(b*8+h)*64+d][2048]
  u16* zws = vTw + (size_t)8192 * 512;

  // bf16 copies of Q/K/V in regions dead until later stages:
  // AbfQ/AbfK in d_out (overwritten only by final gemm_out), AbfV in zws
  // (attn writes zws only after qkv finished reading AbfV).
  u16* AbfQ = (u16*)d_out;
  u16* AbfK = AbfQ + (size_t)8192 * 512;
  u16* AbfV = zws;

  prep_k<<<dim3(2048, 7), 256, 0, stream>>>(Wq, Wk, Wv, Wo, Wt, Q, K, V,
                                            AbfQ, AbfK, AbfV);
  qkv_k<<<dim3(256, 3), 256, 0, stream>>>(AbfQ, AbfK, AbfV, Wt, bq, bk, bv, qws);
  attn_k<<<512, 512, 0, stream>>>(qws, kws, vTw, zws);
  gemm_out_k<<<512, 256, 0, stream>>>(zws, Wt + 3 * 262144, bo, out);
}

// Round 20
// 113.961 us; speedup vs baseline: 1.9185x; 1.0031x over previous
//
#include <hip/hip_runtime.h>

// MHA: B=4, S=2048, D_MODEL=512, H=8, D_HEAD=64
// prep (Wt transpose + QKV fp32->bf16) -> qkv GEMMs (gl_lds) ->
// flash attn (r17 structure VERBATIM + XCD block swizzle only) -> out proj GEMM.
// r18/r19 lesson: QBLK=256/mq=2 restructure has an unlocalized deterministic
// bug (not a staging race -- full-barrier variant fails identically).
// Re-anchored on r17 (passed, attn 59.2us); only blockIdx remap added.

typedef unsigned short u16;
typedef __bf16 bf16x8 __attribute__((ext_vector_type(8)));
typedef float  f32x4  __attribute__((ext_vector_type(4)));

__device__ __forceinline__ u16 f2bf(float x) {
  unsigned u = __float_as_uint(x);
  u += 0x7fffu + ((u >> 16) & 1u);   // RNE
  return (u16)(u >> 16);
}

__device__ __forceinline__ unsigned cvtpk(float lo, float hi) {
  unsigned r;
  asm("v_cvt_pk_bf16_f32 %0, %1, %2" : "=v"(r) : "v"(lo), "v"(hi));
  return r;
}

__device__ __forceinline__ f32x4 mfma16(bf16x8 a, bf16x8 b, f32x4 c) {
  return __builtin_amdgcn_mfma_f32_16x16x32_bf16(a, b, c, 0, 0, 0);
}

// async 16B/lane global->LDS; lds dest is wave-uniform base (HW adds lane*16)
__device__ __forceinline__ void gl16(const u16* g, u16* l) {
  __builtin_amdgcn_global_load_lds(
      (const __attribute__((address_space(1))) void*)g,
      (__attribute__((address_space(3))) void*)l, 16, 0, 0);
}

#define MX3(a, b, c) fmaxf(fmaxf((a), (b)), (c))

// ---- prep: Wt transpose (y=0..3) + Q/K/V fp32->bf16 convert (y=4..6) ----
__global__ __launch_bounds__(256) void prep_k(const float* __restrict__ W0,
                                              const float* __restrict__ W1,
                                              const float* __restrict__ W2,
                                              const float* __restrict__ W3,
                                              u16* __restrict__ Wt,
                                              const float* __restrict__ Q,
                                              const float* __restrict__ K,
                                              const float* __restrict__ V,
                                              u16* __restrict__ Oq,
                                              u16* __restrict__ Ok,
                                              u16* __restrict__ Ov) {
  int y = blockIdx.y;
  if (y < 4) {
    if (blockIdx.x >= 1024) return;
    const float* W = y == 0 ? W0 : y == 1 ? W1 : y == 2 ? W2 : W3;
    int idx = blockIdx.x * 256 + threadIdx.x;
    int k = idx >> 9, n = idx & 511;
    Wt[y * 262144 + n * 512 + k] = f2bf(W[idx]);
  } else {
    int sel = y - 4;
    const float* X = sel == 0 ? Q : sel == 1 ? K : V;
    u16* O = sel == 0 ? Oq : sel == 1 ? Ok : Ov;
    size_t i = ((size_t)blockIdx.x * 256 + threadIdx.x) * 8;
    float4 a = *(const float4*)(X + i);
    float4 b = *(const float4*)(X + i + 4);
    uint4 pk = make_uint4(cvtpk(a.x, a.y), cvtpk(a.z, a.w),
                          cvtpk(b.x, b.y), cvtpk(b.z, b.w));
    *(uint4*)(O + i) = pk;
  }
}

// ---- m97-style bf16 GEMM: A[8192x512] @ Bt^T + bias (Bt [n][k] bf16) ----
// OUT_MODE: 0 bf16 [m][n], 1 bf16 vT[(b*8+h)*64+d][s], 2 fp32 [m][n]
template <int OUT_MODE, int BN>
__device__ __forceinline__ void gemm_body(const u16* __restrict__ A,
                                          const u16* __restrict__ Bt,
                                          const float* __restrict__ bias,
                                          void* __restrict__ outp, int bidx) {
  constexpr int NF = BN / 32;
  constexpr int NBN = 512 / BN;
  __shared__ __align__(16) u16 As[128][64];
  __shared__ __align__(16) u16 Bs[BN][64];
  int tid = threadIdx.x;
  int lane = tid & 63, wid = tid >> 6;
  int wm = wid >> 1, wn = wid & 1;
  int lr = lane & 15, lg = lane >> 4;
  int bm = bidx / NBN, bn = bidx % NBN;

  int r0 = tid >> 3;
  int c8s = (tid & 7) ^ (r0 & 7);
  const u16* Ab = A + (size_t)(bm * 128) * 512;
  const u16* Bb = Bt + (size_t)(bn * BN) * 512;

  f32x4 acc[4][NF];
#pragma unroll
  for (int i = 0; i < 4; ++i)
#pragma unroll
    for (int j = 0; j < NF; ++j) {
      f32x4 z = {0.f, 0.f, 0.f, 0.f};
      acc[i][j] = z;
    }

#pragma unroll
  for (int kt = 0; kt < 8; ++kt) {
    int k0 = kt * 64;
#pragma unroll
    for (int i = 0; i < 4; ++i)
      gl16(&Ab[(size_t)(i * 32 + r0) * 512 + k0 + c8s * 8],
           &As[0][0] + i * 2048 + wid * 512);
#pragma unroll
    for (int i = 0; i < BN / 32; ++i)
      gl16(&Bb[(size_t)(i * 32 + r0) * 512 + k0 + c8s * 8],
           &Bs[0][0] + i * 2048 + wid * 512);
    __syncthreads();
#pragma unroll
    for (int kk = 0; kk < 2; ++kk) {
      bf16x8 af[4], bfr[NF];
      int sw = (lr & 7) << 3;
#pragma unroll
      for (int mf = 0; mf < 4; ++mf)
        af[mf] = *(const bf16x8*)&As[wm * 64 + mf * 16 + lr][(kk * 32 + lg * 8) ^ sw];
#pragma unroll
      for (int nf = 0; nf < NF; ++nf)
        bfr[nf] = *(const bf16x8*)&Bs[wn * (BN / 2) + nf * 16 + lr][(kk * 32 + lg * 8) ^ sw];
#pragma unroll
      for (int mf = 0; mf < 4; ++mf)
#pragma unroll
        for (int nf = 0; nf < NF; ++nf)
          acc[mf][nf] = mfma16(af[mf], bfr[nf], acc[mf][nf]);
    }
    __syncthreads();
  }

#pragma unroll
  for (int mf = 0; mf < 4; ++mf) {
#pragma unroll
    for (int nf = 0; nf < NF; ++nf) {
      int m = bm * 128 + wm * 64 + mf * 16 + lg * 4;
      int n = bn * BN + wn * (BN / 2) + nf * 16 + lr;
      float bia = bias[n];
      if (OUT_MODE == 0) {
        u16* o = (u16*)outp;
#pragma unroll
        for (int r = 0; r < 4; ++r)
          o[(size_t)(m + r) * 512 + n] = f2bf(acc[mf][nf][r] + bia);
      } else if (OUT_MODE == 2) {
        float* o = (float*)outp;
#pragma unroll
        for (int r = 0; r < 4; ++r)
          o[(size_t)(m + r) * 512 + n] = acc[mf][nf][r] + bia;
      } else {
        u16* o = (u16*)outp;
        int b = m >> 11, s = m & 2047;
        int h = n >> 6, d = n & 63;
        ushort4 pk = make_ushort4(f2bf(acc[mf][nf][0] + bia), f2bf(acc[mf][nf][1] + bia),
                                  f2bf(acc[mf][nf][2] + bia), f2bf(acc[mf][nf][3] + bia));
        *(ushort4*)&o[(size_t)((b * 8 + h) * 64 + d) * 2048 + s] = pk;
      }
    }
  }
}

__global__ __launch_bounds__(256) void qkv_k(const u16* __restrict__ Aq,
                                             const u16* __restrict__ Ak,
                                             const u16* __restrict__ Av,
                                             const u16* __restrict__ Wt,
                                             const float* __restrict__ bq,
                                             const float* __restrict__ bk,
                                             const float* __restrict__ bv,
                                             u16* __restrict__ outbase) {
  int sel = blockIdx.y;
  const u16* A = sel == 0 ? Aq : sel == 1 ? Ak : Av;
  const float* bia = sel == 0 ? bq : sel == 1 ? bk : bv;
  const u16* Bt = Wt + (size_t)sel * 262144;
  u16* out = outbase + (size_t)sel * 8192 * 512;
  if (sel == 2)
    gemm_body<1, 128>(A, Bt, bia, out, blockIdx.x);
  else
    gemm_body<0, 128>(A, Bt, bia, out, blockIdx.x);
}

__global__ __launch_bounds__(256) void gemm_out_k(const u16* __restrict__ Ap,
                                                  const u16* __restrict__ Bt,
                                                  const float* __restrict__ bias,
                                                  void* __restrict__ outp) {
  gemm_body<2, 64>(Ap, Bt, bias, outp, blockIdx.x);
}

// ---- flash attention r20: r17 structure verbatim + XCD block swizzle ----
// 8 waves/block, QBLK=128 (16 q-rows/wave), K dbuf + V single via gl_lds,
// mid-tile lgkm+vmcnt(1)+barrier, end-tile syncthreads (r17-proven).
__global__ __launch_bounds__(512) void attn_k(const u16* __restrict__ q,
                                              const u16* __restrict__ kmat,
                                              const u16* __restrict__ vT,
                                              u16* __restrict__ z) {
  __shared__ __align__(16) u16 Ks[2][64][64];   // [buf][key][d], swizzled content
  __shared__ __align__(16) u16 Vs[64][64];      // [d][key], swizzled content
  __shared__ __align__(16) u16 Ps[8][16][72];   // per-wave P[q][key]
  const float C = 0.125f * 1.44269504f;         // 1/sqrt(64) * log2(e)
  int tid = threadIdx.x;
  int lane = tid & 63, w = tid >> 6;            // w = 0..7
  int lr = lane & 15, lg = lane >> 4;
  // XCD swizzle (bijective, 512 % 8 == 0): XCD x owns wgs [x*64, x*64+64)
  // = 4 consecutive bh -> 2MB K/V per XCD L2. Pure blockIdx remap.
  int wg = blockIdx.x;
  int wgs = (wg & 7) * 64 + (wg >> 3);
  int bh = wgs >> 4, qt = wgs & 15;
  int b = bh >> 3, h = bh & 7;
  size_t qrow0 = (size_t)(b * 2048 + qt * 128 + w * 16);

  bf16x8 qf[2];
#pragma unroll
  for (int kf = 0; kf < 2; ++kf)
    qf[kf] = *(const bf16x8*)&q[(qrow0 + lr) * 512 + h * 64 + kf * 32 + lg * 8];

  f32x4 oacc[4];
#pragma unroll
  for (int j = 0; j < 4; ++j) {
    f32x4 zf = {0.f, 0.f, 0.f, 0.f};
    oacc[j] = zf;
  }
  float m = -1e30f, l_part = 0.f, negmC = 0.f;

  const u16* kbase = kmat + (size_t)(b * 2048) * 512 + h * 64;
  const u16* vbase = vT + (size_t)(bh * 64) * 2048;

  int r0 = tid >> 3;                         // 0..63 (512 threads cover 64 rows)
  int c8s = (tid & 7) ^ (r0 & 7);
  int sw = (lr & 7) << 3;                    // fragment-read swizzle (row&7 == lr&7)
  // prologue: K(0) -> buf0 (one gl16/thread covers the whole 64x64 tile)
  gl16(&kbase[(size_t)r0 * 512 + c8s * 8], &Ks[0][0][0] + w * 512);
  asm volatile("s_waitcnt vmcnt(0)" ::: "memory");
  __syncthreads();

  // one KV tile; Kc = current K buffer (literal per call site), Kn = next
  auto tile = [&](int kt, const u16* Kc, u16* Kn) {
    // issue V(kt) (waited mid-tile via vmcnt), then K(kt+1) (stays in flight)
    gl16(&vbase[(size_t)r0 * 2048 + kt * 64 + c8s * 8], &Vs[0][0] + w * 512);
    if (kt < 31)
      gl16(&kbase[(size_t)((kt + 1) * 64 + r0) * 512 + c8s * 8], Kn + w * 512);

    // S^T = K @ Q^T : sacc[nf][r] = S[q=lr][key = nf*16 + lg*4 + r]
    f32x4 sacc[4];
#pragma unroll
    for (int j = 0; j < 4; ++j) {
      f32x4 zf = {0.f, 0.f, 0.f, 0.f};
      sacc[j] = zf;
    }
#pragma unroll
    for (int kf = 0; kf < 2; ++kf) {
#pragma unroll
      for (int nf = 0; nf < 4; ++nf) {
        int row = nf * 16 + lr;
        bf16x8 kb = *(const bf16x8*)&Kc[row * 64 + ((kf * 32 + lg * 8) ^ sw)];
        sacc[nf] = mfma16(kb, qf[kf], sacc[nf]);
      }
    }

    // lane-local 16-value max via max3 triples (8 ops)
    float t0 = MX3(sacc[0][0], sacc[0][1], sacc[0][2]);
    float t1 = MX3(sacc[0][3], sacc[1][0], sacc[1][1]);
    float t2 = MX3(sacc[1][2], sacc[1][3], sacc[2][0]);
    float t3 = MX3(sacc[2][1], sacc[2][2], sacc[2][3]);
    float t4 = MX3(sacc[3][0], sacc[3][1], sacc[3][2]);
    float mxl = fmaxf(MX3(t0, t1, t2), MX3(t3, t4, sacc[3][3]));

    // defer-max: lane-local test exact; shuffles + rescale only in rare branch
    if (!__all(mxl - m <= 8.f)) {
      float mx = fmaxf(mxl, __shfl_xor(mxl, 16));
      mx = fmaxf(mx, __shfl_xor(mx, 32));
      float mnew = fmaxf(m, mx);
      float sc = __builtin_amdgcn_exp2f((m - mnew) * C);
      m = mnew;
      negmC = -m * C;
      l_part *= sc;
#pragma unroll
      for (int nfo = 0; nfo < 4; ++nfo)
#pragma unroll
        for (int r = 0; r < 4; ++r) oacc[nfo][r] *= sc;
    }

    // P = exp2(S*C - m*C); per-lane partial sum; pack to Ps
    float rsum = 0.f;
#pragma unroll
    for (int nf = 0; nf < 4; ++nf) {
      float p0 = __builtin_amdgcn_exp2f(fmaf(sacc[nf][0], C, negmC));
      float p1 = __builtin_amdgcn_exp2f(fmaf(sacc[nf][1], C, negmC));
      float p2 = __builtin_amdgcn_exp2f(fmaf(sacc[nf][2], C, negmC));
      float p3 = __builtin_amdgcn_exp2f(fmaf(sacc[nf][3], C, negmC));
      rsum += (p0 + p1) + (p2 + p3);
      uint2 pw = make_uint2(cvtpk(p0, p1), cvtpk(p2, p3));
      *(uint2*)&Ps[w][lr][nf * 16 + lg * 4] = pw;
    }
    l_part += rsum;

    // order Ps writes before Ps reads; wait V(kt) landed (K prefetch in flight)
    asm volatile("s_waitcnt lgkmcnt(0)" ::: "memory");
    if (kt < 31) {
      asm volatile("s_waitcnt vmcnt(1)" ::: "memory");
    } else {
      asm volatile("s_waitcnt vmcnt(0)" ::: "memory");
    }
    __builtin_amdgcn_s_barrier();

    // O^T += V^T @ P^T
#pragma unroll
    for (int ks = 0; ks < 2; ++ks) {
      bf16x8 pa = *(const bf16x8*)&Ps[w][lr][ks * 32 + lg * 8];
#pragma unroll
      for (int nfo = 0; nfo < 4; ++nfo) {
        int row = nfo * 16 + lr;
        bf16x8 vbr = *(const bf16x8*)&Vs[row][(ks * 32 + lg * 8) ^ sw];
        oacc[nfo] = mfma16(vbr, pa, oacc[nfo]);
      }
    }
    __syncthreads();
  };

  for (int ko = 0; ko < 32; ko += 2) {
    tile(ko,     &Ks[0][0][0], &Ks[1][0][0]);
    tile(ko + 1, &Ks[1][0][0], &Ks[0][0][0]);
  }

  // combine per-lane l partials once (row = lanes {lr, lr+16, lr+32, lr+48})
  float l = l_part + __shfl_xor(l_part, 16);
  l += __shfl_xor(l, 32);
  float rl = 1.f / l;
#pragma unroll
  for (int nfo = 0; nfo < 4; ++nfo) {
    uint2 pw = make_uint2(cvtpk(oacc[nfo][0] * rl, oacc[nfo][1] * rl),
                          cvtpk(oacc[nfo][2] * rl, oacc[nfo][3] * rl));
    *(uint2*)&z[(qrow0 + lr) * 512 + h * 64 + nfo * 16 + lg * 4] = pw;
  }
}

extern "C" void kernel_launch(void* const* d_in, const int* in_sizes, int n_in,
                              void* d_out, int out_size, void* d_ws, size_t ws_size,
                              hipStream_t stream) {
  const float* Q  = (const float*)d_in[0];
  const float* K  = (const float*)d_in[1];
  const float* V  = (const float*)d_in[2];
  const float* Wq = (const float*)d_in[3];
  const float* bq = (const float*)d_in[4];
  const float* Wk = (const float*)d_in[5];
  const float* bk = (const float*)d_in[6];
  const float* Wv = (const float*)d_in[7];
  const float* bv = (const float*)d_in[8];
  const float* Wo = (const float*)d_in[9];
  const float* bo = (const float*)d_in[10];
  float* out = (float*)d_out;

  u16* ws  = (u16*)d_ws;
  u16* Wt  = ws;                                   // 4 x 512*512 (q,k,v,o)
  u16* qws = Wt + 4 * 262144;                      // 8192*512 each
  u16* kws = qws + (size_t)8192 * 512;
  u16* vTw = kws + (size_t)8192 * 512;             // [(b*8+h)*64+d][2048]
  u16* zws = vTw + (size_t)8192 * 512;

  // bf16 copies of Q/K/V in regions dead until later stages:
  // AbfQ/AbfK in d_out (overwritten only by final gemm_out), AbfV in zws
  // (attn writes zws only after qkv finished reading AbfV).
  u16* AbfQ = (u16*)d_out;
  u16* AbfK = AbfQ + (size_t)8192 * 512;
  u16* AbfV = zws;

  prep_k<<<dim3(2048, 7), 256, 0, stream>>>(Wq, Wk, Wv, Wo, Wt, Q, K, V,
                                            AbfQ, AbfK, AbfV);
  qkv_k<<<dim3(256, 3), 256, 0, stream>>>(AbfQ, AbfK, AbfV, Wt, bq, bk, bv, qws);
  attn_k<<<512, 512, 0, stream>>>(qws, kws, vTw, zws);
  gemm_out_k<<<512, 256, 0, stream>>>(zws, Wt + 3 * 262144, bo, out);
}

// Round 21
// 104.919 us; speedup vs baseline: 2.0839x; 1.0862x over previous
//
#include <hip/hip_runtime.h>

// MHA: B=4, S=2048, D_MODEL=512, H=8, D_HEAD=64
// prep (Wt transpose + QKV fp32->bf16) -> qkv GEMMs (gl_lds + XCD swizzle) ->
// flash attn (r21: r20 + V double-buffer -> ONE barrier/tile; r9-proven sync,
// no occupancy cost since grid-limited 2 blocks/CU) -> out proj GEMM (swizzled).

typedef unsigned short u16;
typedef __bf16 bf16x8 __attribute__((ext_vector_type(8)));
typedef float  f32x4  __attribute__((ext_vector_type(4)));

__device__ __forceinline__ u16 f2bf(float x) {
  unsigned u = __float_as_uint(x);
  u += 0x7fffu + ((u >> 16) & 1u);   // RNE
  return (u16)(u >> 16);
}

__device__ __forceinline__ unsigned cvtpk(float lo, float hi) {
  unsigned r;
  asm("v_cvt_pk_bf16_f32 %0, %1, %2" : "=v"(r) : "v"(lo), "v"(hi));
  return r;
}

__device__ __forceinline__ f32x4 mfma16(bf16x8 a, bf16x8 b, f32x4 c) {
  return __builtin_amdgcn_mfma_f32_16x16x32_bf16(a, b, c, 0, 0, 0);
}

// async 16B/lane global->LDS; lds dest is wave-uniform base (HW adds lane*16)
__device__ __forceinline__ void gl16(const u16* g, u16* l) {
  __builtin_amdgcn_global_load_lds(
      (const __attribute__((address_space(1))) void*)g,
      (__attribute__((address_space(3))) void*)l, 16, 0, 0);
}

#define MX3(a, b, c) fmaxf(fmaxf((a), (b)), (c))

// ---- prep: Wt transpose (y=0..3) + Q/K/V fp32->bf16 convert (y=4..6) ----
__global__ __launch_bounds__(256) void prep_k(const float* __restrict__ W0,
                                              const float* __restrict__ W1,
                                              const float* __restrict__ W2,
                                              const float* __restrict__ W3,
                                              u16* __restrict__ Wt,
                                              const float* __restrict__ Q,
                                              const float* __restrict__ K,
                                              const float* __restrict__ V,
                                              u16* __restrict__ Oq,
                                              u16* __restrict__ Ok,
                                              u16* __restrict__ Ov) {
  int y = blockIdx.y;
  if (y < 4) {
    if (blockIdx.x >= 1024) return;
    const float* W = y == 0 ? W0 : y == 1 ? W1 : y == 2 ? W2 : W3;
    int idx = blockIdx.x * 256 + threadIdx.x;
    int k = idx >> 9, n = idx & 511;
    Wt[y * 262144 + n * 512 + k] = f2bf(W[idx]);
  } else {
    int sel = y - 4;
    const float* X = sel == 0 ? Q : sel == 1 ? K : V;
    u16* O = sel == 0 ? Oq : sel == 1 ? Ok : Ov;
    size_t i = ((size_t)blockIdx.x * 256 + threadIdx.x) * 8;
    float4 a = *(const float4*)(X + i);
    float4 b = *(const float4*)(X + i + 4);
    uint4 pk = make_uint4(cvtpk(a.x, a.y), cvtpk(a.z, a.w),
                          cvtpk(b.x, b.y), cvtpk(b.z, b.w));
    *(uint4*)(O + i) = pk;
  }
}

// ---- m97-style bf16 GEMM: A[8192x512] @ Bt^T + bias (Bt [n][k] bf16) ----
// OUT_MODE: 0 bf16 [m][n], 1 bf16 vT[(b*8+h)*64+d][s], 2 fp32 [m][n]
template <int OUT_MODE, int BN>
__device__ __forceinline__ void gemm_body(const u16* __restrict__ A,
                                          const u16* __restrict__ Bt,
                                          const float* __restrict__ bias,
                                          void* __restrict__ outp, int bidx) {
  constexpr int NF = BN / 32;
  constexpr int NBN = 512 / BN;
  __shared__ __align__(16) u16 As[128][64];
  __shared__ __align__(16) u16 Bs[BN][64];
  int tid = threadIdx.x;
  int lane = tid & 63, wid = tid >> 6;
  int wm = wid >> 1, wn = wid & 1;
  int lr = lane & 15, lg = lane >> 4;
  int bm = bidx / NBN, bn = bidx % NBN;

  int r0 = tid >> 3;
  int c8s = (tid & 7) ^ (r0 & 7);
  const u16* Ab = A + (size_t)(bm * 128) * 512;
  const u16* Bb = Bt + (size_t)(bn * BN) * 512;

  f32x4 acc[4][NF];
#pragma unroll
  for (int i = 0; i < 4; ++i)
#pragma unroll
    for (int j = 0; j < NF; ++j) {
      f32x4 z = {0.f, 0.f, 0.f, 0.f};
      acc[i][j] = z;
    }

#pragma unroll
  for (int kt = 0; kt < 8; ++kt) {
    int k0 = kt * 64;
#pragma unroll
    for (int i = 0; i < 4; ++i)
      gl16(&Ab[(size_t)(i * 32 + r0) * 512 + k0 + c8s * 8],
           &As[0][0] + i * 2048 + wid * 512);
#pragma unroll
    for (int i = 0; i < BN / 32; ++i)
      gl16(&Bb[(size_t)(i * 32 + r0) * 512 + k0 + c8s * 8],
           &Bs[0][0] + i * 2048 + wid * 512);
    __syncthreads();
#pragma unroll
    for (int kk = 0; kk < 2; ++kk) {
      bf16x8 af[4], bfr[NF];
      int sw = (lr & 7) << 3;
#pragma unroll
      for (int mf = 0; mf < 4; ++mf)
        af[mf] = *(const bf16x8*)&As[wm * 64 + mf * 16 + lr][(kk * 32 + lg * 8) ^ sw];
#pragma unroll
      for (int nf = 0; nf < NF; ++nf)
        bfr[nf] = *(const bf16x8*)&Bs[wn * (BN / 2) + nf * 16 + lr][(kk * 32 + lg * 8) ^ sw];
#pragma unroll
      for (int mf = 0; mf < 4; ++mf)
#pragma unroll
        for (int nf = 0; nf < NF; ++nf)
          acc[mf][nf] = mfma16(af[mf], bfr[nf], acc[mf][nf]);
    }
    __syncthreads();
  }

#pragma unroll
  for (int mf = 0; mf < 4; ++mf) {
#pragma unroll
    for (int nf = 0; nf < NF; ++nf) {
      int m = bm * 128 + wm * 64 + mf * 16 + lg * 4;
      int n = bn * BN + wn * (BN / 2) + nf * 16 + lr;
      float bia = bias[n];
      if (OUT_MODE == 0) {
        u16* o = (u16*)outp;
#pragma unroll
        for (int r = 0; r < 4; ++r)
          o[(size_t)(m + r) * 512 + n] = f2bf(acc[mf][nf][r] + bia);
      } else if (OUT_MODE == 2) {
        float* o = (float*)outp;
#pragma unroll
        for (int r = 0; r < 4; ++r)
          o[(size_t)(m + r) * 512 + n] = acc[mf][nf][r] + bia;
      } else {
        u16* o = (u16*)outp;
        int b = m >> 11, s = m & 2047;
        int h = n >> 6, d = n & 63;
        ushort4 pk = make_ushort4(f2bf(acc[mf][nf][0] + bia), f2bf(acc[mf][nf][1] + bia),
                                  f2bf(acc[mf][nf][2] + bia), f2bf(acc[mf][nf][3] + bia));
        *(ushort4*)&o[(size_t)((b * 8 + h) * 64 + d) * 2048 + s] = pk;
      }
    }
  }
}

__global__ __launch_bounds__(256) void qkv_k(const u16* __restrict__ Aq,
                                             const u16* __restrict__ Ak,
                                             const u16* __restrict__ Av,
                                             const u16* __restrict__ Wt,
                                             const float* __restrict__ bq,
                                             const float* __restrict__ bk,
                                             const float* __restrict__ bv,
                                             u16* __restrict__ outbase) {
  int sel = blockIdx.y;
  const u16* A = sel == 0 ? Aq : sel == 1 ? Ak : Av;
  const float* bia = sel == 0 ? bq : sel == 1 ? bk : bv;
  const u16* Bt = Wt + (size_t)sel * 262144;
  u16* out = outbase + (size_t)sel * 8192 * 512;
  // XCD swizzle (256 % 8 == 0, bijective): each XCD owns 32 consecutive block
  // ids = 8 full A-panels (4 bn each) -> A panel fetched once per XCD L2.
  int wg = blockIdx.x;
  int wgs = (wg & 7) * 32 + (wg >> 3);
  if (sel == 2)
    gemm_body<1, 128>(A, Bt, bia, out, wgs);
  else
    gemm_body<0, 128>(A, Bt, bia, out, wgs);
}

__global__ __launch_bounds__(256) void gemm_out_k(const u16* __restrict__ Ap,
                                                  const u16* __restrict__ Bt,
                                                  const float* __restrict__ bias,
                                                  void* __restrict__ outp) {
  // XCD swizzle (512 % 8 == 0): 64 consecutive ids = 8 A-panels per XCD.
  int wg = blockIdx.x;
  int wgs = (wg & 7) * 64 + (wg >> 3);
  gemm_body<2, 64>(Ap, Bt, bias, outp, wgs);
}

// ---- flash attention r21: r20 compute + V dbuf, ONE barrier per tile ----
// 8 waves/block, QBLK=128 (16 q-rows/wave), K[2]/V[2] via gl_lds, XCD swizzle.
// Sync: K(kt+1),V(kt+1) issued at tile top; Ps ordered by lgkm fence +
// sched_barrier (r6/r7/r16-proven); end-of-tile vmcnt(0)+syncthreads drains
// both prefetches (order-robust full drain, r19 lesson).
__global__ __launch_bounds__(512) void attn_k(const u16* __restrict__ q,
                                              const u16* __restrict__ kmat,
                                              const u16* __restrict__ vT,
                                              u16* __restrict__ z) {
  __shared__ __align__(16) u16 Ks[2][64][64];   // [buf][key][d], swizzled content
  __shared__ __align__(16) u16 Vs[2][64][64];   // [buf][d][key], swizzled content
  __shared__ __align__(16) u16 Ps[8][16][72];   // per-wave P[q][key]
  const float C = 0.125f * 1.44269504f;         // 1/sqrt(64) * log2(e)
  int tid = threadIdx.x;
  int lane = tid & 63, w = tid >> 6;            // w = 0..7
  int lr = lane & 15, lg = lane >> 4;
  // XCD swizzle (bijective, 512 % 8 == 0): XCD x owns 4 consecutive bh.
  int wg = blockIdx.x;
  int wgs = (wg & 7) * 64 + (wg >> 3);
  int bh = wgs >> 4, qt = wgs & 15;
  int b = bh >> 3, h = bh & 7;
  size_t qrow0 = (size_t)(b * 2048 + qt * 128 + w * 16);

  bf16x8 qf[2];
#pragma unroll
  for (int kf = 0; kf < 2; ++kf)
    qf[kf] = *(const bf16x8*)&q[(qrow0 + lr) * 512 + h * 64 + kf * 32 + lg * 8];

  f32x4 oacc[4];
#pragma unroll
  for (int j = 0; j < 4; ++j) {
    f32x4 zf = {0.f, 0.f, 0.f, 0.f};
    oacc[j] = zf;
  }
  float m = -1e30f, l_part = 0.f, negmC = 0.f;

  const u16* kbase = kmat + (size_t)(b * 2048) * 512 + h * 64;
  const u16* vbase = vT + (size_t)(bh * 64) * 2048;

  int r0 = tid >> 3;                         // 0..63 (512 threads cover 64 rows)
  int c8s = (tid & 7) ^ (r0 & 7);
  int sw = (lr & 7) << 3;                    // fragment-read swizzle (row&7 == lr&7)
  // prologue: K(0),V(0) -> buf0
  gl16(&kbase[(size_t)r0 * 512 + c8s * 8], &Ks[0][0][0] + w * 512);
  gl16(&vbase[(size_t)r0 * 2048 + c8s * 8], &Vs[0][0][0] + w * 512);
  asm volatile("s_waitcnt vmcnt(0)" ::: "memory");
  __syncthreads();

  // one KV tile; cur buffers passed as literal pointers per call site
  auto tile = [&](int kt, const u16* Kc, u16* Kn, const u16* Vc, u16* Vn) {
    // issue K(kt+1), V(kt+1) into the buffers freed at last tile's barrier
    if (kt < 31) {
      gl16(&kbase[(size_t)((kt + 1) * 64 + r0) * 512 + c8s * 8], Kn + w * 512);
      gl16(&vbase[(size_t)r0 * 2048 + (kt + 1) * 64 + c8s * 8], Vn + w * 512);
    }

    // S^T = K @ Q^T : sacc[nf][r] = S[q=lr][key = nf*16 + lg*4 + r]
    f32x4 sacc[4];
#pragma unroll
    for (int j = 0; j < 4; ++j) {
      f32x4 zf = {0.f, 0.f, 0.f, 0.f};
      sacc[j] = zf;
    }
#pragma unroll
    for (int kf = 0; kf < 2; ++kf) {
#pragma unroll
      for (int nf = 0; nf < 4; ++nf) {
        int row = nf * 16 + lr;
        bf16x8 kb = *(const bf16x8*)&Kc[row * 64 + ((kf * 32 + lg * 8) ^ sw)];
        sacc[nf] = mfma16(kb, qf[kf], sacc[nf]);
      }
    }

    // lane-local 16-value max via max3 triples (8 ops)
    float t0 = MX3(sacc[0][0], sacc[0][1], sacc[0][2]);
    float t1 = MX3(sacc[0][3], sacc[1][0], sacc[1][1]);
    float t2 = MX3(sacc[1][2], sacc[1][3], sacc[2][0]);
    float t3 = MX3(sacc[2][1], sacc[2][2], sacc[2][3]);
    float t4 = MX3(sacc[3][0], sacc[3][1], sacc[3][2]);
    float mxl = fmaxf(MX3(t0, t1, t2), MX3(t3, t4, sacc[3][3]));

    // defer-max: lane-local test exact; shuffles + rescale only in rare branch
    if (!__all(mxl - m <= 8.f)) {
      float mx = fmaxf(mxl, __shfl_xor(mxl, 16));
      mx = fmaxf(mx, __shfl_xor(mx, 32));
      float mnew = fmaxf(m, mx);
      float sc = __builtin_amdgcn_exp2f((m - mnew) * C);
      m = mnew;
      negmC = -m * C;
      l_part *= sc;
#pragma unroll
      for (int nfo = 0; nfo < 4; ++nfo)
#pragma unroll
        for (int r = 0; r < 4; ++r) oacc[nfo][r] *= sc;
    }

    // P = exp2(S*C - m*C); per-lane partial sum; pack to Ps
    float rsum = 0.f;
#pragma unroll
    for (int nf = 0; nf < 4; ++nf) {
      float p0 = __builtin_amdgcn_exp2f(fmaf(sacc[nf][0], C, negmC));
      float p1 = __builtin_amdgcn_exp2f(fmaf(sacc[nf][1], C, negmC));
      float p2 = __builtin_amdgcn_exp2f(fmaf(sacc[nf][2], C, negmC));
      float p3 = __builtin_amdgcn_exp2f(fmaf(sacc[nf][3], C, negmC));
      rsum += (p0 + p1) + (p2 + p3);
      uint2 pw = make_uint2(cvtpk(p0, p1), cvtpk(p2, p3));
      *(uint2*)&Ps[w][lr][nf * 16 + lg * 4] = pw;
    }
    l_part += rsum;

    // Ps write->read ordering (wave-private): proven fence pair.
    // V(kt) is resident since last tile's full barrier -- no V wait needed.
    asm volatile("s_waitcnt lgkmcnt(0)" ::: "memory");
    __builtin_amdgcn_sched_barrier(0);

    // O^T += V^T @ P^T
#pragma unroll
    for (int ks = 0; ks < 2; ++ks) {
      bf16x8 pa = *(const bf16x8*)&Ps[w][lr][ks * 32 + lg * 8];
#pragma unroll
      for (int nfo = 0; nfo < 4; ++nfo) {
        int row = nfo * 16 + lr;
        bf16x8 vbr = *(const bf16x8*)&Vc[row * 64 + ((ks * 32 + lg * 8) ^ sw)];
        oacc[nfo] = mfma16(vbr, pa, oacc[nfo]);
      }
    }

    // single end-of-tile barrier: drains K(kt+1)+V(kt+1) (vmcnt 0) and
    // synchronizes buffer reuse; order-robust (full drain).
    asm volatile("s_waitcnt vmcnt(0)" ::: "memory");
    __syncthreads();
  };

  for (int ko = 0; ko < 32; ko += 2) {
    tile(ko,     &Ks[0][0][0], &Ks[1][0][0], &Vs[0][0][0], &Vs[1][0][0]);
    tile(ko + 1, &Ks[1][0][0], &Ks[0][0][0], &Vs[1][0][0], &Vs[0][0][0]);
  }

  // combine per-lane l partials once (row = lanes {lr, lr+16, lr+32, lr+48})
  float l = l_part + __shfl_xor(l_part, 16);
  l += __shfl_xor(l, 32);
  float rl = 1.f / l;
#pragma unroll
  for (int nfo = 0; nfo < 4; ++nfo) {
    uint2 pw = make_uint2(cvtpk(oacc[nfo][0] * rl, oacc[nfo][1] * rl),
                          cvtpk(oacc[nfo][2] * rl, oacc[nfo][3] * rl));
    *(uint2*)&z[(qrow0 + lr) * 512 + h * 64 + nfo * 16 + lg * 4] = pw;
  }
}

extern "C" void kernel_launch(void* const* d_in, const int* in_sizes, int n_in,
                              void* d_out, int out_size, void* d_ws, size_t ws_size,
                              hipStream_t stream) {
  const float* Q  = (const float*)d_in[0];
  const float* K  = (const float*)d_in[1];
  const float* V  = (const float*)d_in[2];
  const float* Wq = (const float*)d_in[3];
  const float* bq = (const float*)d_in[4];
  const float* Wk = (const float*)d_in[5];
  const float* bk = (const float*)d_in[6];
  const float* Wv = (const float*)d_in[7];
  const float* bv = (const float*)d_in[8];
  const float* Wo = (const float*)d_in[9];
  const float* bo = (const float*)d_in[10];
  float* out = (float*)d_out;

  u16* ws  = (u16*)d_ws;
  u16* Wt  = ws;                                   // 4 x 512*512 (q,k,v,o)
  u16* qws = Wt + 4 * 262144;                      // 8192*512 each
  u16* kws = qws + (size_t)8192 * 512;
  u16* vTw = kws + (size_t)8192 * 512;             // [(b*8+h)*64+d][2048]
  u16* zws = vTw + (size_t)8192 * 512;

  // bf16 copies of Q/K/V in regions dead until later stages:
  // AbfQ/AbfK in d_out (overwritten only by final gemm_out), AbfV in zws
  // (attn writes zws only after qkv finished reading AbfV).
  u16* AbfQ = (u16*)d_out;
  u16* AbfK = AbfQ + (size_t)8192 * 512;
  u16* AbfV = zws;

  prep_k<<<dim3(2048, 7), 256, 0, stream>>>(Wq, Wk, Wv, Wo, Wt, Q, K, V,
                                            AbfQ, AbfK, AbfV);
  qkv_k<<<dim3(256, 3), 256, 0, stream>>>(AbfQ, AbfK, AbfV, Wt, bq, bk, bv, qws);
  attn_k<<<512, 512, 0, stream>>>(qws, kws, vTw, zws);
  gemm_out_k<<<512, 256, 0, stream>>>(zws, Wt + 3 * 262144, bo, out);
}